// Round 3
// baseline (1300.958 us; speedup 1.0000x reference)
//
#include <hip/hip_runtime.h>
#include <cfloat>

// Problem constants
#define B_   4
#define C_   512
#define HW_  4096          // 64*64
#define R_   16384         // B_*HW_ rows of x
#define N_   16384         // memory bank rows
#define ALPHA_ 0.1f
#define SCALE_ ((float)(1000.0/49152.0))

#define NCHUNK 4           // R7 config (verified best)

typedef unsigned int u32;
typedef unsigned short u16;
typedef unsigned char u8;
typedef __attribute__((ext_vector_type(2))) unsigned long long u64x2;  // 16B = 2 fp8 frags
typedef __attribute__((ext_vector_type(4))) float f32x4;
typedef __attribute__((ext_vector_type(4))) int i32x4;                 // 16B half-operand
typedef __attribute__((ext_vector_type(8))) int i32x8;                 // 32B MX operand

typedef const __attribute__((address_space(1))) u32* gas_u32;
typedef __attribute__((address_space(3))) u32* las_u32;

__device__ __forceinline__ void async16(const void* g, void* l) {
    __builtin_amdgcn_global_load_lds((gas_u32)g, (las_u32)l, 16, 0, 0);
}

// concat two 16B vectors into one 32B MFMA operand — register-only (no union/memory)
__device__ __forceinline__ i32x8 cat32(i32x4 lo, i32x4 hi) {
    return __builtin_shufflevector(lo, hi, 0, 1, 2, 3, 4, 5, 6, 7);
}

__device__ __forceinline__ u32 pk_fp8x4(float a, float b, float c, float d) {
    u32 v = __builtin_amdgcn_cvt_pk_fp8_f32(a, b, 0, false);   // bytes 0,1
    v = __builtin_amdgcn_cvt_pk_fp8_f32(c, d, v, true);        // bytes 2,3
    return v;
}

__device__ __forceinline__ void ins6(float (&t)[6], float v) {
    if (v < t[5]) {                     // rarely taken
        t[5] = v;
        #pragma unroll
        for (int q = 5; q >= 1; --q) {
            float lo = fminf(t[q-1], t[q]);
            float hi = fmaxf(t[q-1], t[q]);
            t[q-1] = lo; t[q] = hi;
        }
    }
}

// ---------- mem fp32 -> Mb fp8 + m2 (exact fp32 norms) ----------
__global__ void conv_mem_kernel(const float* __restrict__ mem,
                                u8* __restrict__ Mb, float* __restrict__ m2) {
    int w = threadIdx.x >> 6, l = threadIdx.x & 63;
    int row = blockIdx.x * 4 + w;
    const float4* p = (const float4*)(mem + (size_t)row * C_);
    float4 a = p[l], b = p[l + 64];
    float s = a.x*a.x + a.y*a.y + a.z*a.z + a.w*a.w
            + b.x*b.x + b.y*b.y + b.z*b.z + b.w*b.w;
    *(u32*)(Mb + (size_t)row * C_ + l*4)       = pk_fp8x4(a.x, a.y, a.z, a.w);
    *(u32*)(Mb + (size_t)row * C_ + 256 + l*4) = pk_fp8x4(b.x, b.y, b.z, b.w);
    #pragma unroll
    for (int off = 32; off > 0; off >>= 1) s += __shfl_down(s, off);
    if (l == 0) m2[row] = s;
}

// ---------- phi [b][c][n] -> Xb[g][c] fp8 (transpose via LDS) + fused x2 atomics ----------
__global__ void conv_phi_kernel(const float* __restrict__ phi, u8* __restrict__ Xb,
                                float* __restrict__ x2) {
    __shared__ float T[64][65];
    int t = threadIdx.x;
    int n0 = blockIdx.x * 64, c0 = blockIdx.y * 64, b = blockIdx.z;
    const float* src = phi + ((size_t)b * C_ + c0) * HW_ + n0;
    int l = t & 63, cg = t >> 6;
    float sq = 0.f;
    #pragma unroll
    for (int p = 0; p < 16; ++p) {
        int c = cg + p * 4;
        float v = src[(size_t)c * HW_ + l];      // coalesced along n
        T[c][l] = v;
        sq = fmaf(v, v, sq);
    }
    atomicAdd(&x2[(size_t)b * HW_ + n0 + l], sq);
    __syncthreads();
    int cq = t & 15, gl0 = t >> 4;
    #pragma unroll
    for (int p = 0; p < 4; ++p) {
        int gl = gl0 + p * 16;
        u32 v = pk_fp8x4(T[cq*4+0][gl], T[cq*4+1][gl],
                         T[cq*4+2][gl], T[cq*4+3][gl]);
        size_t g = (size_t)b * HW_ + n0 + gl;
        *(u32*)(Xb + g * C_ + c0 + cq*4) = v;
    }
}

// ---------- main GEMM+topk, R12 structure:
//  R11's MX-scaled MFMA (semantics PROVEN correct: R11 absmax=0) with the spill
//  fixed:
//   * no unions — 32B operands built with __builtin_shufflevector (reg-only);
//   * A fragments NOT resident: reloaded per stage from global (L2-hot, 64KB
//     working set per block, nt-invariant). Live A regs 64 -> 16.
//  Register budget @ launch_bounds(256,2) (unified 256/wave):
//     ~16(A) + 64(bv) + 48(top) + ~30 misc VGPR + 64 AGPR(acc) ~ 225 -> no spill.
//  Skeleton otherwise = R10 (M-only dbuf LDS, 1 barrier/stage, verified).
//  K-mapping invariance: A and B bytes fetched with the same logical-chunk
//  function (canonical rq*16 for A; pc-unswizzle for B), halves concatenated
//  in the same order -> positional A[i]*B[i] pairing sums our k-set exactly.
// ----------
__global__ __launch_bounds__(256, 2) void gemm_topk_kernel(
    const u8* __restrict__ Xb, const u8* __restrict__ Mb,
    const float* __restrict__ m2, float* __restrict__ P /* [R][NCHUNK][6] */) {
    __shared__ __align__(16) u8 smem[32768];   // M dbuf: buf b at b*16384, half h at +h*8192
    const int t = threadIdx.x;
    const int w = t >> 6, l = t & 63;
    const int g0  = blockIdx.x * 128;
    const int n0c = blockIdx.y * (N_ / NCHUNK);
    const int rh  = w * 32;             // wave's 32-row band
    const int fm  = l & 15;
    const int rq  = l >> 4;
    // frag read: physical chunk = rq ^ ((fm>>1)&3)  (verified conflict-free, R5/R7)
    const int pc  = (rq ^ ((fm >> 1) & 3)) * 16;
    // staging swizzle (verified R7)
    const int srow4 = l >> 2;
    const int soff  = (((l & 3) ^ ((l >> 3) & 3)) * 16);

    // A row bases (canonical logical chunk rq*16 of each wave row)
    const u8* Xr0 = Xb + (size_t)(g0 + rh +  0 + fm) * C_ + rq * 16;
    const u8* Xr1 = Xb + (size_t)(g0 + rh + 16 + fm) * C_ + rq * 16;

    float top[8][6];                     // row-slot = rh + m*16 + rq*4 + j
    #pragma unroll
    for (int s8 = 0; s8 < 8; ++s8)
        #pragma unroll
        for (int q = 0; q < 6; ++q) top[s8][q] = FLT_MAX;

    // prologue: stage (nt=0, s=0) into buf0
    {
        const u8* Msrc = Mb + (size_t)(n0c + rh) * C_;
        #pragma unroll
        for (int h = 0; h < 2; ++h)
            #pragma unroll
            for (int i = 0; i < 2; ++i)
                async16(Msrc + (size_t)(i*16 + srow4) * C_ + h*64 + soff,
                        smem + rh*64 + h*8192 + i*1024);
    }
    __syncthreads();                     // drains vmcnt(0): buf0 ready

    const int NT = N_ / NCHUNK / 128;    // 32
    #pragma unroll 1
    for (int nt = 0; nt < NT; ++nt) {
        const int n0 = n0c + nt * 128;

        float m2w[8];
        #pragma unroll
        for (int n = 0; n < 8; ++n) m2w[n] = m2[n0 + n * 16 + fm];

        f32x4 acc[2][8];
        #pragma unroll
        for (int m = 0; m < 2; ++m)
            #pragma unroll
            for (int n = 0; n < 8; ++n) acc[m][n] = (f32x4)0.f;

        #pragma unroll
        for (int s = 0; s < 4; ++s) {    // K=128 per stage; buf index = s&1 (nt*4 even)
            // ---- A fragments for this stage (L2-hot reload; issued early) ----
            i32x4 a0l = *(const i32x4*)(Xr0 + s*128);
            i32x4 a0h = *(const i32x4*)(Xr0 + s*128 + 64);
            i32x4 a1l = *(const i32x4*)(Xr1 + s*128);
            i32x4 a1h = *(const i32x4*)(Xr1 + s*128 + 64);
            // ---- prefetch next stage into buf^1 (lands during compute below) ----
            {
                const int nt2 = (s == 3) ? nt + 1 : nt;
                const int s2  = (s + 1) & 3;         // compile-time per unrolled s
                if (nt2 < NT) {
                    const u8* Msrc = Mb + (size_t)(n0c + nt2*128 + rh) * C_ + s2*128;
                    u8* dst = smem + ((s+1)&1)*16384 + rh*64;
                    #pragma unroll
                    for (int h = 0; h < 2; ++h)
                        #pragma unroll
                        for (int i = 0; i < 2; ++i)
                            async16(Msrc + (size_t)(i*16 + srow4) * C_ + h*64 + soff,
                                    dst + h*8192 + i*1024);
                }
            }
            // ---- compute current stage from buf s&1 ----
            const u8* bufp = smem + (s&1)*16384;
            i32x8 bv8[8];
            #pragma unroll
            for (int n = 0; n < 8; ++n) {
                i32x4 blo = *(const i32x4*)(bufp +        (n*16 + fm) * 64 + pc);  // half 0
                i32x4 bhi = *(const i32x4*)(bufp + 8192 + (n*16 + fm) * 64 + pc);  // half 1
                bv8[n] = cat32(blo, bhi);
            }
            i32x8 av0 = cat32(a0l, a0h);
            i32x8 av1 = cat32(a1l, a1h);
            // MX-scaled fp8 MFMA, K=128, unit block-scales (e8m0 0x7F = 2^0).
            #pragma unroll
            for (int n = 0; n < 8; ++n)
                acc[0][n] = __builtin_amdgcn_mfma_scale_f32_16x16x128_f8f6f4(
                    av0, bv8[n], acc[0][n], 0, 0,
                    0, 0x7F7F7F7F, 0, 0x7F7F7F7F);
            #pragma unroll
            for (int n = 0; n < 8; ++n)
                acc[1][n] = __builtin_amdgcn_mfma_scale_f32_16x16x128_f8f6f4(
                    av1, bv8[n], acc[1][n], 0, 0,
                    0, 0x7F7F7F7F, 0, 0x7F7F7F7F);

            if (s == 3) {
                // register epilogue: score = m2[c] - 2*dot (x2 added in finalize)
                #pragma unroll
                for (int m = 0; m < 2; ++m)
                    #pragma unroll
                    for (int j = 0; j < 4; ++j) {
                        float d0 = m2w[0] - 2.f * acc[m][0][j];
                        float d1 = m2w[1] - 2.f * acc[m][1][j];
                        float d2 = m2w[2] - 2.f * acc[m][2][j];
                        float d3 = m2w[3] - 2.f * acc[m][3][j];
                        float d4 = m2w[4] - 2.f * acc[m][4][j];
                        float d5 = m2w[5] - 2.f * acc[m][5][j];
                        float d6 = m2w[6] - 2.f * acc[m][6][j];
                        float d7 = m2w[7] - 2.f * acc[m][7][j];
                        float vmin = fminf(fminf(fminf(d0, d1), fminf(d2, d3)),
                                           fminf(fminf(d4, d5), fminf(d6, d7)));
                        float (&tt)[6] = top[m * 4 + j];
                        if (vmin < tt[5]) {      // slow path: rare after first tiles
                            ins6(tt, d0); ins6(tt, d1); ins6(tt, d2); ins6(tt, d3);
                            ins6(tt, d4); ins6(tt, d5); ins6(tt, d6); ins6(tt, d7);
                        }
                    }
            }
            __syncthreads();   // drains vmcnt(0): next buf staged; buf s&1 free
        }
    }

    // final merge: per row, combine 16 fm-lanes' top-6 -> per-chunk top-6 partial.
    // Two passes of 64 rows through reused LDS (stride 97 -> conflict-free reads).
    float* Mg = (float*)smem;            // 64*97 = 6208 floats = 24832 B <= 32768
    #pragma unroll 1
    for (int p = 0; p < 2; ++p) {
        __syncthreads();
        if ((w >> 1) == p) {
            #pragma unroll
            for (int m = 0; m < 2; ++m)
                #pragma unroll
                for (int j = 0; j < 4; ++j) {
                    int lrow = (w & 1) * 32 + m * 16 + rq * 4 + j;
                    #pragma unroll
                    for (int q = 0; q < 6; ++q)
                        Mg[lrow * 97 + fm * 6 + q] = top[m * 4 + j][q];
                }
        }
        __syncthreads();
        if (t < 64) {
            float t6[6];
            #pragma unroll
            for (int q = 0; q < 6; ++q) t6[q] = FLT_MAX;
            const float* row = Mg + t * 97;
            for (int v = 0; v < 96; ++v) ins6(t6, row[v]);
            float* dst = P + ((size_t)(g0 + p * 64 + t) * NCHUNK + blockIdx.y) * 6;
            #pragma unroll
            for (int q = 0; q < 6; ++q) dst[q] = t6[q];
        }
    }
}

// ---------- merge chunks + hinge loss ----------
__global__ void finalize_kernel(const float* __restrict__ P, const float* __restrict__ x2,
                                const float* __restrict__ rp, float* __restrict__ out) {
    int g = blockIdx.x * 256 + threadIdx.x;
    float t6[6];
    #pragma unroll
    for (int q = 0; q < 6; ++q) t6[q] = FLT_MAX;
    const f32x4* pp = (const f32x4*)(P + (size_t)g * (NCHUNK * 6));
    #pragma unroll
    for (int q = 0; q < NCHUNK * 6 / 4; ++q) {
        f32x4 v = pp[q];
        ins6(t6, v.x); ins6(t6, v.y); ins6(t6, v.z); ins6(t6, v.w);
    }
    float x2g = x2[g];
    float rv = rp[0], r2 = rv * rv;
    float s = 0.f;
    #pragma unroll
    for (int i = 0; i < 3; ++i) {
        float d = fmaxf(t6[i] + x2g, 0.f);
        s += fmaxf(d - r2, 0.f);
    }
    #pragma unroll
    for (int i = 3; i < 6; ++i) {
        float d = fmaxf(t6[i] + x2g, 0.f);
        s += fmaxf(r2 - d - ALPHA_, 0.f);
    }
    #pragma unroll
    for (int off = 32; off > 0; off >>= 1) s += __shfl_down(s, off);
    __shared__ float red[4];
    int w = threadIdx.x >> 6, l = threadIdx.x & 63;
    if (l == 0) red[w] = s;
    __syncthreads();
    if (threadIdx.x == 0)
        atomicAdd(out, (red[0] + red[1] + red[2] + red[3]) * SCALE_);
}

// ================= Round-1 fp32 fallback (used only if ws too small) =================
#define TM 64
#define TN 64
#define KC 64
#define LDP 68

__global__ void m2_kernel(const float* __restrict__ mem, float* __restrict__ m2) {
    int wave = threadIdx.x >> 6, lane = threadIdx.x & 63;
    int row = blockIdx.x * 4 + wave;
    const float4* p = reinterpret_cast<const float4*>(mem + (size_t)row * C_);
    float4 a = p[lane], b = p[lane + 64];
    float s = a.x*a.x + a.y*a.y + a.z*a.z + a.w*a.w
            + b.x*b.x + b.y*b.y + b.z*b.z + b.w*b.w;
    #pragma unroll
    for (int off = 32; off > 0; off >>= 1) s += __shfl_down(s, off);
    if (lane == 0) m2[row] = s;
}

__global__ void x2f_kernel(const float* __restrict__ phi, float* __restrict__ x2) {
    int g = blockIdx.x * blockDim.x + threadIdx.x;
    int b = g >> 12;
    int n = g & 4095;
    const float* p = phi + (size_t)b * C_ * HW_ + n;
    float s = 0.f;
    #pragma unroll 8
    for (int c = 0; c < C_; ++c) {
        float v = p[(size_t)c * HW_];
        s = fmaf(v, v, s);
    }
    x2[g] = s;
}

__global__ __launch_bounds__(256) void dist_loss_kernel(
    const float* __restrict__ phi, const float* __restrict__ mem,
    const float* __restrict__ rp,  const float* __restrict__ m2,
    const float* __restrict__ x2,  float* __restrict__ out) {
    __shared__ float smem[2 * TM * LDP];
    float* xs = smem;
    float* ms = smem + TM * LDP;
    const int tid = threadIdx.x;
    const int tx = tid & 15, ty = tid >> 4;
    const int g0 = blockIdx.x * TM;
    const int b = g0 >> 12, n0img = g0 & 4095;
    const float* phiB = phi + (size_t)b * C_ * HW_ + n0img;
    float top[4][6];
    #pragma unroll
    for (int i = 0; i < 4; ++i)
        #pragma unroll
        for (int q = 0; q < 6; ++q) top[i][q] = FLT_MAX;
    float x2v[4];
    #pragma unroll
    for (int i = 0; i < 4; ++i) x2v[i] = x2[g0 + ty * 4 + i];
    for (int nt = 0; nt < N_ / TN; ++nt) {
        const int n0 = nt * TN;
        float acc[4][4];
        #pragma unroll
        for (int i = 0; i < 4; ++i)
            #pragma unroll
            for (int j = 0; j < 4; ++j) acc[i][j] = 0.f;
        for (int s = 0; s < C_ / KC; ++s) {
            const int k0 = s * KC;
            {
                int rr = tid & 63, cb = tid >> 6;
                #pragma unroll
                for (int p = 0; p < 16; ++p) {
                    int cc = p * 4 + cb;
                    xs[rr * LDP + cc] = phiB[(size_t)(k0 + cc) * HW_ + rr];
                }
            }
            {
                int kq = tid & 15, cb = tid >> 4;
                #pragma unroll
                for (int p = 0; p < 4; ++p) {
                    int c = p * 16 + cb;
                    float4 v = *reinterpret_cast<const float4*>(
                        mem + (size_t)(n0 + c) * C_ + k0 + kq * 4);
                    ms[(kq*4+0)*LDP + c] = v.x; ms[(kq*4+1)*LDP + c] = v.y;
                    ms[(kq*4+2)*LDP + c] = v.z; ms[(kq*4+3)*LDP + c] = v.w;
                }
            }
            __syncthreads();
            #pragma unroll
            for (int kq = 0; kq < KC / 4; ++kq) {
                float4 xa[4], mb[4];
                #pragma unroll
                for (int i = 0; i < 4; ++i)
                    xa[i] = *reinterpret_cast<const float4*>(&xs[(ty*4+i)*LDP + kq*4]);
                #pragma unroll
                for (int kk = 0; kk < 4; ++kk)
                    mb[kk] = *reinterpret_cast<const float4*>(&ms[(kq*4+kk)*LDP + tx*4]);
                #pragma unroll
                for (int i = 0; i < 4; ++i) {
                    const float xk[4] = {xa[i].x, xa[i].y, xa[i].z, xa[i].w};
                    #pragma unroll
                    for (int kk = 0; kk < 4; ++kk) {
                        const float mc[4] = {mb[kk].x, mb[kk].y, mb[kk].z, mb[kk].w};
                        #pragma unroll
                        for (int j = 0; j < 4; ++j)
                            acc[i][j] = fmaf(xk[kk], mc[j], acc[i][j]);
                    }
                }
            }
            __syncthreads();
        }
        #pragma unroll
        for (int j = 0; j < 4; ++j) {
            float m2v = m2[n0 + tx * 4 + j];
            #pragma unroll
            for (int i = 0; i < 4; ++i) {
                float d = fmaxf(x2v[i] + m2v - 2.f * acc[i][j], 0.f);
                ins6(top[i], d);
            }
        }
    }
    __syncthreads();
    float* mg = smem;
    #pragma unroll
    for (int i = 0; i < 4; ++i)
        #pragma unroll
        for (int q = 0; q < 6; ++q)
            mg[(ty*4+i)*97 + tx*6 + q] = top[i][q];
    __syncthreads();
    if (tid < 64) {
        float t6[6];
        #pragma unroll
        for (int q = 0; q < 6; ++q) t6[q] = FLT_MAX;
        const float* row = mg + tid * 97;
        for (int v = 0; v < 96; ++v) ins6(t6, row[v]);
        float rv = rp[0], r2 = rv * rv;
        float s = fmaxf(t6[0]-r2,0.f) + fmaxf(t6[1]-r2,0.f) + fmaxf(t6[2]-r2,0.f)
                + fmaxf(r2-t6[3]-ALPHA_,0.f) + fmaxf(r2-t6[4]-ALPHA_,0.f)
                + fmaxf(r2-t6[5]-ALPHA_,0.f);
        #pragma unroll
        for (int off = 32; off > 0; off >>= 1) s += __shfl_down(s, off);
        if (tid == 0) atomicAdd(out, s * SCALE_);
    }
}

extern "C" void kernel_launch(void* const* d_in, const int* in_sizes, int n_in,
                              void* d_out, int out_size, void* d_ws, size_t ws_size,
                              hipStream_t stream) {
    const float* phi = (const float*)d_in[0];
    const float* mem = (const float*)d_in[1];
    const float* rp  = (const float*)d_in[2];
    float* out = (float*)d_out;

    const size_t offX  = 0;
    const size_t offM  = (size_t)R_ * C_;                // Xb fp8: 8 MB
    const size_t offx2 = offM + (size_t)N_ * C_;         // Mb fp8: 8 MB
    const size_t offm2 = offx2 + (size_t)R_ * 4;
    const size_t offP  = offm2 + (size_t)N_ * 4;
    const size_t need  = offP + (size_t)R_ * NCHUNK * 6 * 4;  // ~17.8 MB

    hipMemsetAsync(out, 0, sizeof(float), stream);

    if (ws_size >= need) {
        u8*    Xb = (u8*)((char*)d_ws + offX);
        u8*    Mb = (u8*)((char*)d_ws + offM);
        float* x2 = (float*)((char*)d_ws + offx2);
        float* m2 = (float*)((char*)d_ws + offm2);
        float* P  = (float*)((char*)d_ws + offP);

        hipMemsetAsync(x2, 0, (size_t)R_ * 4, stream);   // x2 accumulated atomically
        conv_mem_kernel<<<N_ / 4, 256, 0, stream>>>(mem, Mb, m2);
        conv_phi_kernel<<<dim3(HW_ / 64, C_ / 64, B_), 256, 0, stream>>>(phi, Xb, x2);
        gemm_topk_kernel<<<dim3(128, NCHUNK), 256, 0, stream>>>(Xb, Mb, m2, P);
        finalize_kernel<<<R_ / 256, 256, 0, stream>>>(P, x2, rp, out);
    } else {
        // fp32 fallback (verified round 1)
        float* m2 = (float*)d_ws;
        float* x2 = m2 + N_;
        m2_kernel<<<N_ / 4, 256, 0, stream>>>(mem, m2);
        x2f_kernel<<<R_ / 256, 256, 0, stream>>>(phi, x2);
        dist_loss_kernel<<<R_ / TM, 256, 0, stream>>>(phi, mem, rp, m2, x2, out);
    }
}

// Round 4
// 1249.513 us; speedup vs baseline: 1.0412x; 1.0412x over previous
//
#include <hip/hip_runtime.h>
#include <cfloat>

// Problem constants
#define B_   4
#define C_   512
#define HW_  4096          // 64*64
#define R_   16384         // B_*HW_ rows of x
#define N_   16384         // memory bank rows
#define ALPHA_ 0.1f
#define SCALE_ ((float)(1000.0/49152.0))

#define NCHUNK 4           // R7 config (verified best)

typedef unsigned int u32;
typedef unsigned short u16;
typedef unsigned char u8;
typedef __attribute__((ext_vector_type(2))) unsigned long long u64x2;  // 16B = 2 fp8 frags
typedef __attribute__((ext_vector_type(4))) float f32x4;
typedef __attribute__((ext_vector_type(4))) int i32x4;                 // 16B half-operand
typedef __attribute__((ext_vector_type(8))) int i32x8;                 // 32B MX operand

typedef const __attribute__((address_space(1))) u32* gas_u32;
typedef __attribute__((address_space(3))) u32* las_u32;

__device__ __forceinline__ void async16(const void* g, void* l) {
    __builtin_amdgcn_global_load_lds((gas_u32)g, (las_u32)l, 16, 0, 0);
}

// concat two 16B vectors into one 32B MFMA operand — register-only (no union/memory)
__device__ __forceinline__ i32x8 cat32(i32x4 lo, i32x4 hi) {
    return __builtin_shufflevector(lo, hi, 0, 1, 2, 3, 4, 5, 6, 7);
}

__device__ __forceinline__ u32 pk_fp8x4(float a, float b, float c, float d) {
    u32 v = __builtin_amdgcn_cvt_pk_fp8_f32(a, b, 0, false);   // bytes 0,1
    v = __builtin_amdgcn_cvt_pk_fp8_f32(c, d, v, true);        // bytes 2,3
    return v;
}

__device__ __forceinline__ void ins6(float (&t)[6], float v) {
    if (v < t[5]) {                     // rarely taken
        t[5] = v;
        #pragma unroll
        for (int q = 5; q >= 1; --q) {
            float lo = fminf(t[q-1], t[q]);
            float hi = fmaxf(t[q-1], t[q]);
            t[q-1] = lo; t[q] = hi;
        }
    }
}

// ---------- mem fp32 -> Mb fp8 + m2 (exact fp32 norms) ----------
__global__ void conv_mem_kernel(const float* __restrict__ mem,
                                u8* __restrict__ Mb, float* __restrict__ m2) {
    int w = threadIdx.x >> 6, l = threadIdx.x & 63;
    int row = blockIdx.x * 4 + w;
    const float4* p = (const float4*)(mem + (size_t)row * C_);
    float4 a = p[l], b = p[l + 64];
    float s = a.x*a.x + a.y*a.y + a.z*a.z + a.w*a.w
            + b.x*b.x + b.y*b.y + b.z*b.z + b.w*b.w;
    *(u32*)(Mb + (size_t)row * C_ + l*4)       = pk_fp8x4(a.x, a.y, a.z, a.w);
    *(u32*)(Mb + (size_t)row * C_ + 256 + l*4) = pk_fp8x4(b.x, b.y, b.z, b.w);
    #pragma unroll
    for (int off = 32; off > 0; off >>= 1) s += __shfl_down(s, off);
    if (l == 0) m2[row] = s;
}

// ---------- phi [b][c][n] -> Xb[g][c] fp8 (transpose via LDS) + fused x2 atomics ----------
__global__ void conv_phi_kernel(const float* __restrict__ phi, u8* __restrict__ Xb,
                                float* __restrict__ x2) {
    __shared__ float T[64][65];
    int t = threadIdx.x;
    int n0 = blockIdx.x * 64, c0 = blockIdx.y * 64, b = blockIdx.z;
    const float* src = phi + ((size_t)b * C_ + c0) * HW_ + n0;
    int l = t & 63, cg = t >> 6;
    float sq = 0.f;
    #pragma unroll
    for (int p = 0; p < 16; ++p) {
        int c = cg + p * 4;
        float v = src[(size_t)c * HW_ + l];      // coalesced along n
        T[c][l] = v;
        sq = fmaf(v, v, sq);
    }
    atomicAdd(&x2[(size_t)b * HW_ + n0 + l], sq);
    __syncthreads();
    int cq = t & 15, gl0 = t >> 4;
    #pragma unroll
    for (int p = 0; p < 4; ++p) {
        int gl = gl0 + p * 16;
        u32 v = pk_fp8x4(T[cq*4+0][gl], T[cq*4+1][gl],
                         T[cq*4+2][gl], T[cq*4+3][gl]);
        size_t g = (size_t)b * HW_ + n0 + gl;
        *(u32*)(Xb + g * C_ + c0 + cq*4) = v;
    }
}

// ---------- main GEMM+topk, R13 structure:
//  MX-scaled MFMA (semantics proven: R11/R12 absmax=0; MFMA-busy matches 4.6PF
//  rate) with the ARCH-VGPR live set shrunk below the 128 accvgpr-split cap
//  (R11/R12 diagnosis: acc in AGPRs -> accum_offset=128 -> arch VGPRs capped
//  at 128; holding bv8[8]=64 regs overflowed -> 4.77GB scratch):
//   * B operands processed ONE AT A TIME (load 2xb128 -> cat -> 2 MFMA -> dead)
//     -> <=16 live B regs instead of 64;
//   * m2 loads moved inside the s==3 epilogue (8 fewer loop-live regs).
//  Live arch set ~ top 48 + av 16 + bv ~16 + ptrs/misc ~30 ~= 110 < 128.
//  Skeleton otherwise = R10 (M-only dbuf LDS, 1 barrier/stage, verified).
//  K-mapping invariance unchanged (canonical rq*16 for A; pc-unswizzle for B;
//  halves concatenated in the same order on both sides).
// ----------
__global__ __launch_bounds__(256, 2) void gemm_topk_kernel(
    const u8* __restrict__ Xb, const u8* __restrict__ Mb,
    const float* __restrict__ m2, float* __restrict__ P /* [R][NCHUNK][6] */) {
    __shared__ __align__(16) u8 smem[32768];   // M dbuf: buf b at b*16384, half h at +h*8192
    const int t = threadIdx.x;
    const int w = t >> 6, l = t & 63;
    const int g0  = blockIdx.x * 128;
    const int n0c = blockIdx.y * (N_ / NCHUNK);
    const int rh  = w * 32;             // wave's 32-row band
    const int fm  = l & 15;
    const int rq  = l >> 4;
    // frag read: physical chunk = rq ^ ((fm>>1)&3)  (verified conflict-free, R5/R7)
    const int pc  = (rq ^ ((fm >> 1) & 3)) * 16;
    // staging swizzle (verified R7)
    const int srow4 = l >> 2;
    const int soff  = (((l & 3) ^ ((l >> 3) & 3)) * 16);

    // A row bases (canonical logical chunk rq*16 of each wave row)
    const u8* Xr0 = Xb + (size_t)(g0 + rh +  0 + fm) * C_ + rq * 16;
    const u8* Xr1 = Xb + (size_t)(g0 + rh + 16 + fm) * C_ + rq * 16;

    float top[8][6];                     // row-slot = rh + m*16 + rq*4 + j
    #pragma unroll
    for (int s8 = 0; s8 < 8; ++s8)
        #pragma unroll
        for (int q = 0; q < 6; ++q) top[s8][q] = FLT_MAX;

    // prologue: stage (nt=0, s=0) into buf0
    {
        const u8* Msrc = Mb + (size_t)(n0c + rh) * C_;
        #pragma unroll
        for (int h = 0; h < 2; ++h)
            #pragma unroll
            for (int i = 0; i < 2; ++i)
                async16(Msrc + (size_t)(i*16 + srow4) * C_ + h*64 + soff,
                        smem + rh*64 + h*8192 + i*1024);
    }
    __syncthreads();                     // drains vmcnt(0): buf0 ready

    const int NT = N_ / NCHUNK / 128;    // 32
    #pragma unroll 1
    for (int nt = 0; nt < NT; ++nt) {
        const int n0 = n0c + nt * 128;

        f32x4 acc[2][8];
        #pragma unroll
        for (int m = 0; m < 2; ++m)
            #pragma unroll
            for (int n = 0; n < 8; ++n) acc[m][n] = (f32x4)0.f;

        #pragma unroll
        for (int s = 0; s < 4; ++s) {    // K=128 per stage; buf index = s&1 (nt*4 even)
            // ---- A fragments for this stage (L2-hot reload; issued early) ----
            i32x4 a0l = *(const i32x4*)(Xr0 + s*128);
            i32x4 a0h = *(const i32x4*)(Xr0 + s*128 + 64);
            i32x4 a1l = *(const i32x4*)(Xr1 + s*128);
            i32x4 a1h = *(const i32x4*)(Xr1 + s*128 + 64);
            // ---- prefetch next stage into buf^1 (lands during compute below) ----
            {
                const int nt2 = (s == 3) ? nt + 1 : nt;
                const int s2  = (s + 1) & 3;         // compile-time per unrolled s
                if (nt2 < NT) {
                    const u8* Msrc = Mb + (size_t)(n0c + nt2*128 + rh) * C_ + s2*128;
                    u8* dst = smem + ((s+1)&1)*16384 + rh*64;
                    #pragma unroll
                    for (int h = 0; h < 2; ++h)
                        #pragma unroll
                        for (int i = 0; i < 2; ++i)
                            async16(Msrc + (size_t)(i*16 + srow4) * C_ + h*64 + soff,
                                    dst + h*8192 + i*1024);
                }
            }
            // ---- compute current stage from buf s&1 ----
            // B operands one at a time: <=2 bv live -> stays under the 128
            // arch-VGPR accvgpr-split cap (the R11/R12 scratch bug).
            const u8* bufp = smem + (s&1)*16384;
            i32x8 av0 = cat32(a0l, a0h);
            i32x8 av1 = cat32(a1l, a1h);
            #pragma unroll
            for (int n = 0; n < 8; ++n) {
                i32x4 blo = *(const i32x4*)(bufp +        (n*16 + fm) * 64 + pc);  // half 0
                i32x4 bhi = *(const i32x4*)(bufp + 8192 + (n*16 + fm) * 64 + pc);  // half 1
                i32x8 bv = cat32(blo, bhi);
                // MX-scaled fp8 MFMA, K=128, unit block-scales (e8m0 0x7F = 2^0).
                acc[0][n] = __builtin_amdgcn_mfma_scale_f32_16x16x128_f8f6f4(
                    av0, bv, acc[0][n], 0, 0,
                    0, 0x7F7F7F7F, 0, 0x7F7F7F7F);
                acc[1][n] = __builtin_amdgcn_mfma_scale_f32_16x16x128_f8f6f4(
                    av1, bv, acc[1][n], 0, 0,
                    0, 0x7F7F7F7F, 0, 0x7F7F7F7F);
            }

            if (s == 3) {
                // register epilogue: score = m2[c] - 2*dot (x2 added in finalize)
                float m2w[8];
                #pragma unroll
                for (int n = 0; n < 8; ++n) m2w[n] = m2[n0 + n * 16 + fm];
                #pragma unroll
                for (int m = 0; m < 2; ++m)
                    #pragma unroll
                    for (int j = 0; j < 4; ++j) {
                        float d0 = m2w[0] - 2.f * acc[m][0][j];
                        float d1 = m2w[1] - 2.f * acc[m][1][j];
                        float d2 = m2w[2] - 2.f * acc[m][2][j];
                        float d3 = m2w[3] - 2.f * acc[m][3][j];
                        float d4 = m2w[4] - 2.f * acc[m][4][j];
                        float d5 = m2w[5] - 2.f * acc[m][5][j];
                        float d6 = m2w[6] - 2.f * acc[m][6][j];
                        float d7 = m2w[7] - 2.f * acc[m][7][j];
                        float vmin = fminf(fminf(fminf(d0, d1), fminf(d2, d3)),
                                           fminf(fminf(d4, d5), fminf(d6, d7)));
                        float (&tt)[6] = top[m * 4 + j];
                        if (vmin < tt[5]) {      // slow path: rare after first tiles
                            ins6(tt, d0); ins6(tt, d1); ins6(tt, d2); ins6(tt, d3);
                            ins6(tt, d4); ins6(tt, d5); ins6(tt, d6); ins6(tt, d7);
                        }
                    }
            }
            __syncthreads();   // drains vmcnt(0): next buf staged; buf s&1 free
        }
    }

    // final merge: per row, combine 16 fm-lanes' top-6 -> per-chunk top-6 partial.
    // Two passes of 64 rows through reused LDS (stride 97 -> conflict-free reads).
    float* Mg = (float*)smem;            // 64*97 = 6208 floats = 24832 B <= 32768
    #pragma unroll 1
    for (int p = 0; p < 2; ++p) {
        __syncthreads();
        if ((w >> 1) == p) {
            #pragma unroll
            for (int m = 0; m < 2; ++m)
                #pragma unroll
                for (int j = 0; j < 4; ++j) {
                    int lrow = (w & 1) * 32 + m * 16 + rq * 4 + j;
                    #pragma unroll
                    for (int q = 0; q < 6; ++q)
                        Mg[lrow * 97 + fm * 6 + q] = top[m * 4 + j][q];
                }
        }
        __syncthreads();
        if (t < 64) {
            float t6[6];
            #pragma unroll
            for (int q = 0; q < 6; ++q) t6[q] = FLT_MAX;
            const float* row = Mg + t * 97;
            for (int v = 0; v < 96; ++v) ins6(t6, row[v]);
            float* dst = P + ((size_t)(g0 + p * 64 + t) * NCHUNK + blockIdx.y) * 6;
            #pragma unroll
            for (int q = 0; q < 6; ++q) dst[q] = t6[q];
        }
    }
}

// ---------- merge chunks + hinge loss ----------
__global__ void finalize_kernel(const float* __restrict__ P, const float* __restrict__ x2,
                                const float* __restrict__ rp, float* __restrict__ out) {
    int g = blockIdx.x * 256 + threadIdx.x;
    float t6[6];
    #pragma unroll
    for (int q = 0; q < 6; ++q) t6[q] = FLT_MAX;
    const f32x4* pp = (const f32x4*)(P + (size_t)g * (NCHUNK * 6));
    #pragma unroll
    for (int q = 0; q < NCHUNK * 6 / 4; ++q) {
        f32x4 v = pp[q];
        ins6(t6, v.x); ins6(t6, v.y); ins6(t6, v.z); ins6(t6, v.w);
    }
    float x2g = x2[g];
    float rv = rp[0], r2 = rv * rv;
    float s = 0.f;
    #pragma unroll
    for (int i = 0; i < 3; ++i) {
        float d = fmaxf(t6[i] + x2g, 0.f);
        s += fmaxf(d - r2, 0.f);
    }
    #pragma unroll
    for (int i = 3; i < 6; ++i) {
        float d = fmaxf(t6[i] + x2g, 0.f);
        s += fmaxf(r2 - d - ALPHA_, 0.f);
    }
    #pragma unroll
    for (int off = 32; off > 0; off >>= 1) s += __shfl_down(s, off);
    __shared__ float red[4];
    int w = threadIdx.x >> 6, l = threadIdx.x & 63;
    if (l == 0) red[w] = s;
    __syncthreads();
    if (threadIdx.x == 0)
        atomicAdd(out, (red[0] + red[1] + red[2] + red[3]) * SCALE_);
}

// ================= Round-1 fp32 fallback (used only if ws too small) =================
#define TM 64
#define TN 64
#define KC 64
#define LDP 68

__global__ void m2_kernel(const float* __restrict__ mem, float* __restrict__ m2) {
    int wave = threadIdx.x >> 6, lane = threadIdx.x & 63;
    int row = blockIdx.x * 4 + wave;
    const float4* p = reinterpret_cast<const float4*>(mem + (size_t)row * C_);
    float4 a = p[lane], b = p[lane + 64];
    float s = a.x*a.x + a.y*a.y + a.z*a.z + a.w*a.w
            + b.x*b.x + b.y*b.y + b.z*b.z + b.w*b.w;
    #pragma unroll
    for (int off = 32; off > 0; off >>= 1) s += __shfl_down(s, off);
    if (lane == 0) m2[row] = s;
}

__global__ void x2f_kernel(const float* __restrict__ phi, float* __restrict__ x2) {
    int g = blockIdx.x * blockDim.x + threadIdx.x;
    int b = g >> 12;
    int n = g & 4095;
    const float* p = phi + (size_t)b * C_ * HW_ + n;
    float s = 0.f;
    #pragma unroll 8
    for (int c = 0; c < C_; ++c) {
        float v = p[(size_t)c * HW_];
        s = fmaf(v, v, s);
    }
    x2[g] = s;
}

__global__ __launch_bounds__(256) void dist_loss_kernel(
    const float* __restrict__ phi, const float* __restrict__ mem,
    const float* __restrict__ rp,  const float* __restrict__ m2,
    const float* __restrict__ x2,  float* __restrict__ out) {
    __shared__ float smem[2 * TM * LDP];
    float* xs = smem;
    float* ms = smem + TM * LDP;
    const int tid = threadIdx.x;
    const int tx = tid & 15, ty = tid >> 4;
    const int g0 = blockIdx.x * TM;
    const int b = g0 >> 12, n0img = g0 & 4095;
    const float* phiB = phi + (size_t)b * C_ * HW_ + n0img;
    float top[4][6];
    #pragma unroll
    for (int i = 0; i < 4; ++i)
        #pragma unroll
        for (int q = 0; q < 6; ++q) top[i][q] = FLT_MAX;
    float x2v[4];
    #pragma unroll
    for (int i = 0; i < 4; ++i) x2v[i] = x2[g0 + ty * 4 + i];
    for (int nt = 0; nt < N_ / TN; ++nt) {
        const int n0 = nt * TN;
        float acc[4][4];
        #pragma unroll
        for (int i = 0; i < 4; ++i)
            #pragma unroll
            for (int j = 0; j < 4; ++j) acc[i][j] = 0.f;
        for (int s = 0; s < C_ / KC; ++s) {
            const int k0 = s * KC;
            {
                int rr = tid & 63, cb = tid >> 6;
                #pragma unroll
                for (int p = 0; p < 16; ++p) {
                    int cc = p * 4 + cb;
                    xs[rr * LDP + cc] = phiB[(size_t)(k0 + cc) * HW_ + rr];
                }
            }
            {
                int kq = tid & 15, cb = tid >> 4;
                #pragma unroll
                for (int p = 0; p < 4; ++p) {
                    int c = p * 16 + cb;
                    float4 v = *reinterpret_cast<const float4*>(
                        mem + (size_t)(n0 + c) * C_ + k0 + kq * 4);
                    ms[(kq*4+0)*LDP + c] = v.x; ms[(kq*4+1)*LDP + c] = v.y;
                    ms[(kq*4+2)*LDP + c] = v.z; ms[(kq*4+3)*LDP + c] = v.w;
                }
            }
            __syncthreads();
            #pragma unroll
            for (int kq = 0; kq < KC / 4; ++kq) {
                float4 xa[4], mb[4];
                #pragma unroll
                for (int i = 0; i < 4; ++i)
                    xa[i] = *reinterpret_cast<const float4*>(&xs[(ty*4+i)*LDP + kq*4]);
                #pragma unroll
                for (int kk = 0; kk < 4; ++kk)
                    mb[kk] = *reinterpret_cast<const float4*>(&ms[(kq*4+kk)*LDP + tx*4]);
                #pragma unroll
                for (int i = 0; i < 4; ++i) {
                    const float xk[4] = {xa[i].x, xa[i].y, xa[i].z, xa[i].w};
                    #pragma unroll
                    for (int kk = 0; kk < 4; ++kk) {
                        const float mc[4] = {mb[kk].x, mb[kk].y, mb[kk].z, mb[kk].w};
                        #pragma unroll
                        for (int j = 0; j < 4; ++j)
                            acc[i][j] = fmaf(xk[kk], mc[j], acc[i][j]);
                    }
                }
            }
            __syncthreads();
        }
        #pragma unroll
        for (int j = 0; j < 4; ++j) {
            float m2v = m2[n0 + tx * 4 + j];
            #pragma unroll
            for (int i = 0; i < 4; ++i) {
                float d = fmaxf(x2v[i] + m2v - 2.f * acc[i][j], 0.f);
                ins6(top[i], d);
            }
        }
    }
    __syncthreads();
    float* mg = smem;
    #pragma unroll
    for (int i = 0; i < 4; ++i)
        #pragma unroll
        for (int q = 0; q < 6; ++q)
            mg[(ty*4+i)*97 + tx*6 + q] = top[i][q];
    __syncthreads();
    if (tid < 64) {
        float t6[6];
        #pragma unroll
        for (int q = 0; q < 6; ++q) t6[q] = FLT_MAX;
        const float* row = mg + tid * 97;
        for (int v = 0; v < 96; ++v) ins6(t6, row[v]);
        float rv = rp[0], r2 = rv * rv;
        float s = fmaxf(t6[0]-r2,0.f) + fmaxf(t6[1]-r2,0.f) + fmaxf(t6[2]-r2,0.f)
                + fmaxf(r2-t6[3]-ALPHA_,0.f) + fmaxf(r2-t6[4]-ALPHA_,0.f)
                + fmaxf(r2-t6[5]-ALPHA_,0.f);
        #pragma unroll
        for (int off = 32; off > 0; off >>= 1) s += __shfl_down(s, off);
        if (tid == 0) atomicAdd(out, s * SCALE_);
    }
}

extern "C" void kernel_launch(void* const* d_in, const int* in_sizes, int n_in,
                              void* d_out, int out_size, void* d_ws, size_t ws_size,
                              hipStream_t stream) {
    const float* phi = (const float*)d_in[0];
    const float* mem = (const float*)d_in[1];
    const float* rp  = (const float*)d_in[2];
    float* out = (float*)d_out;

    const size_t offX  = 0;
    const size_t offM  = (size_t)R_ * C_;                // Xb fp8: 8 MB
    const size_t offx2 = offM + (size_t)N_ * C_;         // Mb fp8: 8 MB
    const size_t offm2 = offx2 + (size_t)R_ * 4;
    const size_t offP  = offm2 + (size_t)N_ * 4;
    const size_t need  = offP + (size_t)R_ * NCHUNK * 6 * 4;  // ~17.8 MB

    hipMemsetAsync(out, 0, sizeof(float), stream);

    if (ws_size >= need) {
        u8*    Xb = (u8*)((char*)d_ws + offX);
        u8*    Mb = (u8*)((char*)d_ws + offM);
        float* x2 = (float*)((char*)d_ws + offx2);
        float* m2 = (float*)((char*)d_ws + offm2);
        float* P  = (float*)((char*)d_ws + offP);

        hipMemsetAsync(x2, 0, (size_t)R_ * 4, stream);   // x2 accumulated atomically
        conv_mem_kernel<<<N_ / 4, 256, 0, stream>>>(mem, Mb, m2);
        conv_phi_kernel<<<dim3(HW_ / 64, C_ / 64, B_), 256, 0, stream>>>(phi, Xb, x2);
        gemm_topk_kernel<<<dim3(128, NCHUNK), 256, 0, stream>>>(Xb, Mb, m2, P);
        finalize_kernel<<<R_ / 256, 256, 0, stream>>>(P, x2, rp, out);
    } else {
        // fp32 fallback (verified round 1)
        float* m2 = (float*)d_ws;
        float* x2 = m2 + N_;
        m2_kernel<<<N_ / 4, 256, 0, stream>>>(mem, m2);
        x2f_kernel<<<R_ / 256, 256, 0, stream>>>(phi, x2);
        dist_loss_kernel<<<R_ / TM, 256, 0, stream>>>(phi, mem, rp, m2, x2, out);
    }
}

// Round 5
// 739.322 us; speedup vs baseline: 1.7597x; 1.6901x over previous
//
#include <hip/hip_runtime.h>
#include <cfloat>

// Problem constants
#define B_   4
#define C_   512
#define HW_  4096          // 64*64
#define R_   16384         // B_*HW_ rows of x
#define N_   16384         // memory bank rows
#define ALPHA_ 0.1f
#define SCALE_ ((float)(1000.0/49152.0))

#define NCHUNK 4           // R7 config (verified best)

typedef unsigned int u32;
typedef unsigned short u16;
typedef unsigned char u8;
typedef __attribute__((ext_vector_type(2))) unsigned long long u64x2;  // 16B = 2 fp8 frags
typedef __attribute__((ext_vector_type(4))) float f32x4;

typedef const __attribute__((address_space(1))) u32* gas_u32;
typedef __attribute__((address_space(3))) u32* las_u32;

__device__ __forceinline__ void async16(const void* g, void* l) {
    __builtin_amdgcn_global_load_lds((gas_u32)g, (las_u32)l, 16, 0, 0);
}

__device__ __forceinline__ u32 pk_fp8x4(float a, float b, float c, float d) {
    u32 v = __builtin_amdgcn_cvt_pk_fp8_f32(a, b, 0, false);   // bytes 0,1
    v = __builtin_amdgcn_cvt_pk_fp8_f32(c, d, v, true);        // bytes 2,3
    return v;
}

__device__ __forceinline__ void ins6(float (&t)[6], float v) {
    if (v < t[5]) {                     // rarely taken
        t[5] = v;
        #pragma unroll
        for (int q = 5; q >= 1; --q) {
            float lo = fminf(t[q-1], t[q]);
            float hi = fmaxf(t[q-1], t[q]);
            t[q-1] = lo; t[q] = hi;
        }
    }
}

// ---------- mem fp32 -> Mb fp8 + m2 (exact fp32 norms) ----------
__global__ void conv_mem_kernel(const float* __restrict__ mem,
                                u8* __restrict__ Mb, float* __restrict__ m2) {
    int w = threadIdx.x >> 6, l = threadIdx.x & 63;
    int row = blockIdx.x * 4 + w;
    const float4* p = (const float4*)(mem + (size_t)row * C_);
    float4 a = p[l], b = p[l + 64];
    float s = a.x*a.x + a.y*a.y + a.z*a.z + a.w*a.w
            + b.x*b.x + b.y*b.y + b.z*b.z + b.w*b.w;
    *(u32*)(Mb + (size_t)row * C_ + l*4)       = pk_fp8x4(a.x, a.y, a.z, a.w);
    *(u32*)(Mb + (size_t)row * C_ + 256 + l*4) = pk_fp8x4(b.x, b.y, b.z, b.w);
    #pragma unroll
    for (int off = 32; off > 0; off >>= 1) s += __shfl_down(s, off);
    if (l == 0) m2[row] = s;
}

// ---------- phi [b][c][n] -> Xb[g][c] fp8 (transpose via LDS) + fused x2 atomics ----------
__global__ void conv_phi_kernel(const float* __restrict__ phi, u8* __restrict__ Xb,
                                float* __restrict__ x2) {
    __shared__ float T[64][65];
    int t = threadIdx.x;
    int n0 = blockIdx.x * 64, c0 = blockIdx.y * 64, b = blockIdx.z;
    const float* src = phi + ((size_t)b * C_ + c0) * HW_ + n0;
    int l = t & 63, cg = t >> 6;
    float sq = 0.f;
    #pragma unroll
    for (int p = 0; p < 16; ++p) {
        int c = cg + p * 4;
        float v = src[(size_t)c * HW_ + l];      // coalesced along n
        T[c][l] = v;
        sq = fmaf(v, v, sq);
    }
    atomicAdd(&x2[(size_t)b * HW_ + n0 + l], sq);
    __syncthreads();
    int cq = t & 15, gl0 = t >> 4;
    #pragma unroll
    for (int p = 0; p < 4; ++p) {
        int gl = gl0 + p * 16;
        u32 v = pk_fp8x4(T[cq*4+0][gl], T[cq*4+1][gl],
                         T[cq*4+2][gl], T[cq*4+3][gl]);
        size_t g = (size_t)b * HW_ + n0 + gl;
        *(u32*)(Xb + g * C_ + c0 + cq*4) = v;
    }
}

// ---------- main GEMM+topk, R14 structure:
//  MX abandoned (R11-R13: mfma_scale lowering emits scratch regardless of
//  live-set -> 4.7GB scratch traffic; pre-committed exit). Back to the
//  VERIFIED non-MX fp8 16x16x32 path (R0/R10 semantics, 313us), attacking the
//  ~40% idle share via OCCUPANCY:
//  R0 ran 2 waves/SIMD because unified reg demand = 116 VGPR + 64 AGPR(acc)
//  = 180/wave -> floor(512/180)=2. This version trims the live arch set and
//  requests __launch_bounds__(256,3) -> target 166<=170 regs -> 3 blocks/CU:
//   * A fragments reloaded per stage from global (L2-hot; addressing function
//     proven correct in R12/R13 absmax=0) — transient 16 regs, no LDS;
//   * B processed in PAIRS (8 live B regs, dependent-MFMA distance 4);
//   * m2 loads inside the s==3 epilogue.
//  Skeleton = R10 (M-only dbuf LDS 2x16KB, 1 barrier/stage, verified equal
//  to R0). Staging swizzle + pc-unswizzle byte-identical to R7.
// ----------
__global__ __launch_bounds__(256, 3) void gemm_topk_kernel(
    const u8* __restrict__ Xb, const u8* __restrict__ Mb,
    const float* __restrict__ m2, float* __restrict__ P /* [R][NCHUNK][6] */) {
    __shared__ __align__(16) u8 smem[32768];   // M dbuf: buf b at b*16384, half h at +h*8192
    const int t = threadIdx.x;
    const int w = t >> 6, l = t & 63;
    const int g0  = blockIdx.x * 128;
    const int n0c = blockIdx.y * (N_ / NCHUNK);
    const int rh  = w * 32;             // wave's 32-row band
    const int fm  = l & 15;
    const int rq  = l >> 4;
    // frag read: physical chunk = rq ^ ((fm>>1)&3)  (verified conflict-free, R5/R7)
    const int pc  = (rq ^ ((fm >> 1) & 3)) * 16;
    // staging swizzle (verified R7)
    const int srow4 = l >> 2;
    const int soff  = (((l & 3) ^ ((l >> 3) & 3)) * 16);

    // A row bases (canonical logical chunk rq*16 of each wave row)
    const u8* Xr0 = Xb + (size_t)(g0 + rh +  0 + fm) * C_ + rq * 16;
    const u8* Xr1 = Xb + (size_t)(g0 + rh + 16 + fm) * C_ + rq * 16;

    float top[8][6];                     // row-slot = rh + m*16 + rq*4 + j
    #pragma unroll
    for (int s8 = 0; s8 < 8; ++s8)
        #pragma unroll
        for (int q = 0; q < 6; ++q) top[s8][q] = FLT_MAX;

    // prologue: stage (nt=0, s=0) into buf0
    {
        const u8* Msrc = Mb + (size_t)(n0c + rh) * C_;
        #pragma unroll
        for (int h = 0; h < 2; ++h)
            #pragma unroll
            for (int i = 0; i < 2; ++i)
                async16(Msrc + (size_t)(i*16 + srow4) * C_ + h*64 + soff,
                        smem + rh*64 + h*8192 + i*1024);
    }
    __syncthreads();                     // drains vmcnt(0): buf0 ready

    const int NT = N_ / NCHUNK / 128;    // 32
    #pragma unroll 1
    for (int nt = 0; nt < NT; ++nt) {
        const int n0 = n0c + nt * 128;

        f32x4 acc[2][8];
        #pragma unroll
        for (int m = 0; m < 2; ++m)
            #pragma unroll
            for (int n = 0; n < 8; ++n) acc[m][n] = (f32x4)0.f;

        #pragma unroll
        for (int s = 0; s < 4; ++s) {    // K=128 per stage; buf index = s&1 (nt*4 even)
            // ---- A fragments for this stage (L2-hot reload, transient) ----
            u64x2 a00 = *(const u64x2*)(Xr0 + s*128);        // m=0, half 0
            u64x2 a01 = *(const u64x2*)(Xr0 + s*128 + 64);   // m=0, half 1
            u64x2 a10 = *(const u64x2*)(Xr1 + s*128);        // m=1, half 0
            u64x2 a11 = *(const u64x2*)(Xr1 + s*128 + 64);   // m=1, half 1
            // ---- prefetch next stage into buf^1 (lands during compute below) ----
            {
                const int nt2 = (s == 3) ? nt + 1 : nt;
                const int s2  = (s + 1) & 3;         // compile-time per unrolled s
                if (nt2 < NT) {
                    const u8* Msrc = Mb + (size_t)(n0c + nt2*128 + rh) * C_ + s2*128;
                    u8* dst = smem + ((s+1)&1)*16384 + rh*64;
                    #pragma unroll
                    for (int h = 0; h < 2; ++h)
                        #pragma unroll
                        for (int i = 0; i < 2; ++i)
                            async16(Msrc + (size_t)(i*16 + srow4) * C_ + h*64 + soff,
                                    dst + h*8192 + i*1024);
                }
            }
            // ---- compute current stage from buf s&1 ----
            // B in pairs: 8 live B regs; dependent updates to the same acc are
            // 4 MFMAs apart (x then y) -> latency covered at 3 waves/SIMD.
            const u8* bufp = smem + (s&1)*16384;
            #pragma unroll
            for (int h = 0; h < 2; ++h) {
                const u8* Mh = bufp + h * 8192;
                const u64x2 ax0 = h ? a01 : a00;   // m=0 frag for this half
                const u64x2 ax1 = h ? a11 : a10;   // m=1 frag for this half
                #pragma unroll
                for (int np = 0; np < 4; ++np) {
                    const int n = np * 2;
                    u64x2 b0 = *(const u64x2*)(Mh + ((n+0)*16 + fm) * 64 + pc);
                    u64x2 b1 = *(const u64x2*)(Mh + ((n+1)*16 + fm) * 64 + pc);
                    // kf0 = low 8B, kf1 = high 8B: K-permutation applied
                    // identically to A and B -> same dot product (verified R7).
                    acc[0][n+0] = __builtin_amdgcn_mfma_f32_16x16x32_fp8_fp8(
                        (long)ax0.x, (long)b0.x, acc[0][n+0], 0, 0, 0);
                    acc[1][n+0] = __builtin_amdgcn_mfma_f32_16x16x32_fp8_fp8(
                        (long)ax1.x, (long)b0.x, acc[1][n+0], 0, 0, 0);
                    acc[0][n+1] = __builtin_amdgcn_mfma_f32_16x16x32_fp8_fp8(
                        (long)ax0.x, (long)b1.x, acc[0][n+1], 0, 0, 0);
                    acc[1][n+1] = __builtin_amdgcn_mfma_f32_16x16x32_fp8_fp8(
                        (long)ax1.x, (long)b1.x, acc[1][n+1], 0, 0, 0);
                    acc[0][n+0] = __builtin_amdgcn_mfma_f32_16x16x32_fp8_fp8(
                        (long)ax0.y, (long)b0.y, acc[0][n+0], 0, 0, 0);
                    acc[1][n+0] = __builtin_amdgcn_mfma_f32_16x16x32_fp8_fp8(
                        (long)ax1.y, (long)b0.y, acc[1][n+0], 0, 0, 0);
                    acc[0][n+1] = __builtin_amdgcn_mfma_f32_16x16x32_fp8_fp8(
                        (long)ax0.y, (long)b1.y, acc[0][n+1], 0, 0, 0);
                    acc[1][n+1] = __builtin_amdgcn_mfma_f32_16x16x32_fp8_fp8(
                        (long)ax1.y, (long)b1.y, acc[1][n+1], 0, 0, 0);
                }
            }

            if (s == 3) {
                // register epilogue: score = m2[c] - 2*dot (x2 added in finalize)
                float m2w[8];
                #pragma unroll
                for (int n = 0; n < 8; ++n) m2w[n] = m2[n0 + n * 16 + fm];
                #pragma unroll
                for (int m = 0; m < 2; ++m)
                    #pragma unroll
                    for (int j = 0; j < 4; ++j) {
                        float d0 = m2w[0] - 2.f * acc[m][0][j];
                        float d1 = m2w[1] - 2.f * acc[m][1][j];
                        float d2 = m2w[2] - 2.f * acc[m][2][j];
                        float d3 = m2w[3] - 2.f * acc[m][3][j];
                        float d4 = m2w[4] - 2.f * acc[m][4][j];
                        float d5 = m2w[5] - 2.f * acc[m][5][j];
                        float d6 = m2w[6] - 2.f * acc[m][6][j];
                        float d7 = m2w[7] - 2.f * acc[m][7][j];
                        float vmin = fminf(fminf(fminf(d0, d1), fminf(d2, d3)),
                                           fminf(fminf(d4, d5), fminf(d6, d7)));
                        float (&tt)[6] = top[m * 4 + j];
                        if (vmin < tt[5]) {      // slow path: rare after first tiles
                            ins6(tt, d0); ins6(tt, d1); ins6(tt, d2); ins6(tt, d3);
                            ins6(tt, d4); ins6(tt, d5); ins6(tt, d6); ins6(tt, d7);
                        }
                    }
            }
            __syncthreads();   // drains vmcnt(0): next buf staged; buf s&1 free
        }
    }

    // final merge: per row, combine 16 fm-lanes' top-6 -> per-chunk top-6 partial.
    // Two passes of 64 rows through reused LDS (stride 97 -> conflict-free reads).
    float* Mg = (float*)smem;            // 64*97 = 6208 floats = 24832 B <= 32768
    #pragma unroll 1
    for (int p = 0; p < 2; ++p) {
        __syncthreads();
        if ((w >> 1) == p) {
            #pragma unroll
            for (int m = 0; m < 2; ++m)
                #pragma unroll
                for (int j = 0; j < 4; ++j) {
                    int lrow = (w & 1) * 32 + m * 16 + rq * 4 + j;
                    #pragma unroll
                    for (int q = 0; q < 6; ++q)
                        Mg[lrow * 97 + fm * 6 + q] = top[m * 4 + j][q];
                }
        }
        __syncthreads();
        if (t < 64) {
            float t6[6];
            #pragma unroll
            for (int q = 0; q < 6; ++q) t6[q] = FLT_MAX;
            const float* row = Mg + t * 97;
            for (int v = 0; v < 96; ++v) ins6(t6, row[v]);
            float* dst = P + ((size_t)(g0 + p * 64 + t) * NCHUNK + blockIdx.y) * 6;
            #pragma unroll
            for (int q = 0; q < 6; ++q) dst[q] = t6[q];
        }
    }
}

// ---------- merge chunks + hinge loss ----------
__global__ void finalize_kernel(const float* __restrict__ P, const float* __restrict__ x2,
                                const float* __restrict__ rp, float* __restrict__ out) {
    int g = blockIdx.x * 256 + threadIdx.x;
    float t6[6];
    #pragma unroll
    for (int q = 0; q < 6; ++q) t6[q] = FLT_MAX;
    const f32x4* pp = (const f32x4*)(P + (size_t)g * (NCHUNK * 6));
    #pragma unroll
    for (int q = 0; q < NCHUNK * 6 / 4; ++q) {
        f32x4 v = pp[q];
        ins6(t6, v.x); ins6(t6, v.y); ins6(t6, v.z); ins6(t6, v.w);
    }
    float x2g = x2[g];
    float rv = rp[0], r2 = rv * rv;
    float s = 0.f;
    #pragma unroll
    for (int i = 0; i < 3; ++i) {
        float d = fmaxf(t6[i] + x2g, 0.f);
        s += fmaxf(d - r2, 0.f);
    }
    #pragma unroll
    for (int i = 3; i < 6; ++i) {
        float d = fmaxf(t6[i] + x2g, 0.f);
        s += fmaxf(r2 - d - ALPHA_, 0.f);
    }
    #pragma unroll
    for (int off = 32; off > 0; off >>= 1) s += __shfl_down(s, off);
    __shared__ float red[4];
    int w = threadIdx.x >> 6, l = threadIdx.x & 63;
    if (l == 0) red[w] = s;
    __syncthreads();
    if (threadIdx.x == 0)
        atomicAdd(out, (red[0] + red[1] + red[2] + red[3]) * SCALE_);
}

// ================= Round-1 fp32 fallback (used only if ws too small) =================
#define TM 64
#define TN 64
#define KC 64
#define LDP 68

__global__ void m2_kernel(const float* __restrict__ mem, float* __restrict__ m2) {
    int wave = threadIdx.x >> 6, lane = threadIdx.x & 63;
    int row = blockIdx.x * 4 + wave;
    const float4* p = reinterpret_cast<const float4*>(mem + (size_t)row * C_);
    float4 a = p[lane], b = p[lane + 64];
    float s = a.x*a.x + a.y*a.y + a.z*a.z + a.w*a.w
            + b.x*b.x + b.y*b.y + b.z*b.z + b.w*b.w;
    #pragma unroll
    for (int off = 32; off > 0; off >>= 1) s += __shfl_down(s, off);
    if (lane == 0) m2[row] = s;
}

__global__ void x2f_kernel(const float* __restrict__ phi, float* __restrict__ x2) {
    int g = blockIdx.x * blockDim.x + threadIdx.x;
    int b = g >> 12;
    int n = g & 4095;
    const float* p = phi + (size_t)b * C_ * HW_ + n;
    float s = 0.f;
    #pragma unroll 8
    for (int c = 0; c < C_; ++c) {
        float v = p[(size_t)c * HW_];
        s = fmaf(v, v, s);
    }
    x2[g] = s;
}

__global__ __launch_bounds__(256) void dist_loss_kernel(
    const float* __restrict__ phi, const float* __restrict__ mem,
    const float* __restrict__ rp,  const float* __restrict__ m2,
    const float* __restrict__ x2,  float* __restrict__ out) {
    __shared__ float smem[2 * TM * LDP];
    float* xs = smem;
    float* ms = smem + TM * LDP;
    const int tid = threadIdx.x;
    const int tx = tid & 15, ty = tid >> 4;
    const int g0 = blockIdx.x * TM;
    const int b = g0 >> 12, n0img = g0 & 4095;
    const float* phiB = phi + (size_t)b * C_ * HW_ + n0img;
    float top[4][6];
    #pragma unroll
    for (int i = 0; i < 4; ++i)
        #pragma unroll
        for (int q = 0; q < 6; ++q) top[i][q] = FLT_MAX;
    float x2v[4];
    #pragma unroll
    for (int i = 0; i < 4; ++i) x2v[i] = x2[g0 + ty * 4 + i];
    for (int nt = 0; nt < N_ / TN; ++nt) {
        const int n0 = nt * TN;
        float acc[4][4];
        #pragma unroll
        for (int i = 0; i < 4; ++i)
            #pragma unroll
            for (int j = 0; j < 4; ++j) acc[i][j] = 0.f;
        for (int s = 0; s < C_ / KC; ++s) {
            const int k0 = s * KC;
            {
                int rr = tid & 63, cb = tid >> 6;
                #pragma unroll
                for (int p = 0; p < 16; ++p) {
                    int cc = p * 4 + cb;
                    xs[rr * LDP + cc] = phiB[(size_t)(k0 + cc) * HW_ + rr];
                }
            }
            {
                int kq = tid & 15, cb = tid >> 4;
                #pragma unroll
                for (int p = 0; p < 4; ++p) {
                    int c = p * 16 + cb;
                    float4 v = *reinterpret_cast<const float4*>(
                        mem + (size_t)(n0 + c) * C_ + k0 + kq * 4);
                    ms[(kq*4+0)*LDP + c] = v.x; ms[(kq*4+1)*LDP + c] = v.y;
                    ms[(kq*4+2)*LDP + c] = v.z; ms[(kq*4+3)*LDP + c] = v.w;
                }
            }
            __syncthreads();
            #pragma unroll
            for (int kq = 0; kq < KC / 4; ++kq) {
                float4 xa[4], mb[4];
                #pragma unroll
                for (int i = 0; i < 4; ++i)
                    xa[i] = *reinterpret_cast<const float4*>(&xs[(ty*4+i)*LDP + kq*4]);
                #pragma unroll
                for (int kk = 0; kk < 4; ++kk)
                    mb[kk] = *reinterpret_cast<const float4*>(&ms[(kq*4+kk)*LDP + tx*4]);
                #pragma unroll
                for (int i = 0; i < 4; ++i) {
                    const float xk[4] = {xa[i].x, xa[i].y, xa[i].z, xa[i].w};
                    #pragma unroll
                    for (int kk = 0; kk < 4; ++kk) {
                        const float mc[4] = {mb[kk].x, mb[kk].y, mb[kk].z, mb[kk].w};
                        #pragma unroll
                        for (int j = 0; j < 4; ++j)
                            acc[i][j] = fmaf(xk[kk], mc[j], acc[i][j]);
                    }
                }
            }
            __syncthreads();
        }
        #pragma unroll
        for (int j = 0; j < 4; ++j) {
            float m2v = m2[n0 + tx * 4 + j];
            #pragma unroll
            for (int i = 0; i < 4; ++i) {
                float d = fmaxf(x2v[i] + m2v - 2.f * acc[i][j], 0.f);
                ins6(top[i], d);
            }
        }
    }
    __syncthreads();
    float* mg = smem;
    #pragma unroll
    for (int i = 0; i < 4; ++i)
        #pragma unroll
        for (int q = 0; q < 6; ++q)
            mg[(ty*4+i)*97 + tx*6 + q] = top[i][q];
    __syncthreads();
    if (tid < 64) {
        float t6[6];
        #pragma unroll
        for (int q = 0; q < 6; ++q) t6[q] = FLT_MAX;
        const float* row = mg + tid * 97;
        for (int v = 0; v < 96; ++v) ins6(t6, row[v]);
        float rv = rp[0], r2 = rv * rv;
        float s = fmaxf(t6[0]-r2,0.f) + fmaxf(t6[1]-r2,0.f) + fmaxf(t6[2]-r2,0.f)
                + fmaxf(r2-t6[3]-ALPHA_,0.f) + fmaxf(r2-t6[4]-ALPHA_,0.f)
                + fmaxf(r2-t6[5]-ALPHA_,0.f);
        #pragma unroll
        for (int off = 32; off > 0; off >>= 1) s += __shfl_down(s, off);
        if (tid == 0) atomicAdd(out, s * SCALE_);
    }
}

extern "C" void kernel_launch(void* const* d_in, const int* in_sizes, int n_in,
                              void* d_out, int out_size, void* d_ws, size_t ws_size,
                              hipStream_t stream) {
    const float* phi = (const float*)d_in[0];
    const float* mem = (const float*)d_in[1];
    const float* rp  = (const float*)d_in[2];
    float* out = (float*)d_out;

    const size_t offX  = 0;
    const size_t offM  = (size_t)R_ * C_;                // Xb fp8: 8 MB
    const size_t offx2 = offM + (size_t)N_ * C_;         // Mb fp8: 8 MB
    const size_t offm2 = offx2 + (size_t)R_ * 4;
    const size_t offP  = offm2 + (size_t)N_ * 4;
    const size_t need  = offP + (size_t)R_ * NCHUNK * 6 * 4;  // ~17.8 MB

    hipMemsetAsync(out, 0, sizeof(float), stream);

    if (ws_size >= need) {
        u8*    Xb = (u8*)((char*)d_ws + offX);
        u8*    Mb = (u8*)((char*)d_ws + offM);
        float* x2 = (float*)((char*)d_ws + offx2);
        float* m2 = (float*)((char*)d_ws + offm2);
        float* P  = (float*)((char*)d_ws + offP);

        hipMemsetAsync(x2, 0, (size_t)R_ * 4, stream);   // x2 accumulated atomically
        conv_mem_kernel<<<N_ / 4, 256, 0, stream>>>(mem, Mb, m2);
        conv_phi_kernel<<<dim3(HW_ / 64, C_ / 64, B_), 256, 0, stream>>>(phi, Xb, x2);
        gemm_topk_kernel<<<dim3(128, NCHUNK), 256, 0, stream>>>(Xb, Mb, m2, P);
        finalize_kernel<<<R_ / 256, 256, 0, stream>>>(P, x2, rp, out);
    } else {
        // fp32 fallback (verified round 1)
        float* m2 = (float*)d_ws;
        float* x2 = m2 + N_;
        m2_kernel<<<N_ / 4, 256, 0, stream>>>(mem, m2);
        x2f_kernel<<<R_ / 256, 256, 0, stream>>>(phi, x2);
        dist_loss_kernel<<<R_ / TM, 256, 0, stream>>>(phi, mem, rp, m2, x2, out);
    }
}

// Round 6
// 348.554 us; speedup vs baseline: 3.7324x; 2.1211x over previous
//
#include <hip/hip_runtime.h>
#include <cfloat>

// Problem constants
#define B_   4
#define C_   512
#define HW_  4096          // 64*64
#define R_   16384         // B_*HW_ rows of x
#define N_   16384         // memory bank rows
#define ALPHA_ 0.1f
#define SCALE_ ((float)(1000.0/49152.0))

#define NCHUNK 4           // R7 config (verified best)

typedef unsigned int u32;
typedef unsigned short u16;
typedef unsigned char u8;
typedef __attribute__((ext_vector_type(2))) unsigned long long u64x2;  // 16B = 2 fp8 frags
typedef __attribute__((ext_vector_type(4))) float f32x4;

typedef const __attribute__((address_space(1))) u32* gas_u32;
typedef __attribute__((address_space(3))) u32* las_u32;

__device__ __forceinline__ void async16(const void* g, void* l) {
    __builtin_amdgcn_global_load_lds((gas_u32)g, (las_u32)l, 16, 0, 0);
}

__device__ __forceinline__ u32 pk_fp8x4(float a, float b, float c, float d) {
    u32 v = __builtin_amdgcn_cvt_pk_fp8_f32(a, b, 0, false);   // bytes 0,1
    v = __builtin_amdgcn_cvt_pk_fp8_f32(c, d, v, true);        // bytes 2,3
    return v;
}

__device__ __forceinline__ void ins6(float (&t)[6], float v) {
    if (v < t[5]) {                     // rarely taken
        t[5] = v;
        #pragma unroll
        for (int q = 5; q >= 1; --q) {
            float lo = fminf(t[q-1], t[q]);
            float hi = fmaxf(t[q-1], t[q]);
            t[q-1] = lo; t[q] = hi;
        }
    }
}

// ---------- mem fp32 -> Mb fp8 + m2 (exact fp32 norms) ----------
__global__ void conv_mem_kernel(const float* __restrict__ mem,
                                u8* __restrict__ Mb, float* __restrict__ m2) {
    int w = threadIdx.x >> 6, l = threadIdx.x & 63;
    int row = blockIdx.x * 4 + w;
    const float4* p = (const float4*)(mem + (size_t)row * C_);
    float4 a = p[l], b = p[l + 64];
    float s = a.x*a.x + a.y*a.y + a.z*a.z + a.w*a.w
            + b.x*b.x + b.y*b.y + b.z*b.z + b.w*b.w;
    *(u32*)(Mb + (size_t)row * C_ + l*4)       = pk_fp8x4(a.x, a.y, a.z, a.w);
    *(u32*)(Mb + (size_t)row * C_ + 256 + l*4) = pk_fp8x4(b.x, b.y, b.z, b.w);
    #pragma unroll
    for (int off = 32; off > 0; off >>= 1) s += __shfl_down(s, off);
    if (l == 0) m2[row] = s;
}

// ---------- phi [b][c][n] -> Xb[g][c] fp8 (transpose via LDS) + fused x2 atomics ----------
__global__ void conv_phi_kernel(const float* __restrict__ phi, u8* __restrict__ Xb,
                                float* __restrict__ x2) {
    __shared__ float T[64][65];
    int t = threadIdx.x;
    int n0 = blockIdx.x * 64, c0 = blockIdx.y * 64, b = blockIdx.z;
    const float* src = phi + ((size_t)b * C_ + c0) * HW_ + n0;
    int l = t & 63, cg = t >> 6;
    float sq = 0.f;
    #pragma unroll
    for (int p = 0; p < 16; ++p) {
        int c = cg + p * 4;
        float v = src[(size_t)c * HW_ + l];      // coalesced along n
        T[c][l] = v;
        sq = fmaf(v, v, sq);
    }
    atomicAdd(&x2[(size_t)b * HW_ + n0 + l], sq);
    __syncthreads();
    int cq = t & 15, gl0 = t >> 4;
    #pragma unroll
    for (int p = 0; p < 4; ++p) {
        int gl = gl0 + p * 16;
        u32 v = pk_fp8x4(T[cq*4+0][gl], T[cq*4+1][gl],
                         T[cq*4+2][gl], T[cq*4+3][gl]);
        size_t g = (size_t)b * HW_ + n0 + gl;
        *(u32*)(Xb + g * C_ + c0 + cq*4) = v;
    }
}

// ---------- main GEMM+topk, R15 structure: 16-ROW WAVES for occupancy.
//  R14 lesson: the 32-row wave's state (top 48 + acc 64 AGPR) makes unified
//  demand ~185 -> forcing a 170 cap spills (1 GB scratch). Fix is structural:
//  wave owns 16 output rows x 128 cols ->
//     acc[8] = 32 AGPR (was 64), top[4][6] = 24 regs (was 48),
//     A register-resident for the WHOLE block = 32 regs loaded once
//     (addressing verified in R12-R14, absmax=0; kills R14's A L2-thrash).
//  Estimated unified ~125-135 -> 3-4 waves/SIMD with __launch_bounds__(256,3)
//  (cap 170 >> demand -> no spill by construction).
//  Block tile 64x128 (4 waves), grid.x = R/64 = 256. Accepted cost: each wave
//  reads the full B tile for half the MFMAs (LDS pipe ~2x per W) — still
//  below the current 2935 cyc/W wall, and 12-16 waves/CU overlap pipes.
//  M staging/swizzle/dbuf/1-barrier-per-stage byte-identical to R10 (verified;
//  staging bands mband = w*32 cover all 128 M rows). B frag read (pc) and
//  epilogue mapping identical to R0 with the m-index dropped.
// ----------
__global__ __launch_bounds__(256, 3) void gemm_topk_kernel(
    const u8* __restrict__ Xb, const u8* __restrict__ Mb,
    const float* __restrict__ m2, float* __restrict__ P /* [R][NCHUNK][6] */) {
    __shared__ __align__(16) u8 smem[32768];   // M dbuf: buf b at b*16384, half h at +h*8192
    const int t = threadIdx.x;
    const int w = t >> 6, l = t & 63;
    const int g0  = blockIdx.x * 64;            // block's 64 output rows
    const int n0c = blockIdx.y * (N_ / NCHUNK);
    const int mband = w * 32;                   // staging band of M rows (as R10's rh)
    const int fm  = l & 15;
    const int rq  = l >> 4;
    // frag read: physical chunk = rq ^ ((fm>>1)&3)  (verified conflict-free, R5/R7)
    const int pc  = (rq ^ ((fm >> 1) & 3)) * 16;
    // staging swizzle (verified R7)
    const int srow4 = l >> 2;
    const int soff  = (((l & 3) ^ ((l >> 3) & 3)) * 16);

    // ---- A register-resident for the whole block: wave w owns rows g0+w*16..+16.
    // Per lane: row g0+w*16+fm, canonical logical chunk rq*16 of each 64-B half
    // of each K=128 window. 8 x u64x2 = 32 regs, statically indexed (rule #20).
    u64x2 ax[4][2];
    {
        const u8* Xr = Xb + (size_t)(g0 + w*16 + fm) * C_ + rq * 16;
        #pragma unroll
        for (int s = 0; s < 4; ++s) {
            ax[s][0] = *(const u64x2*)(Xr + s*128);
            ax[s][1] = *(const u64x2*)(Xr + s*128 + 64);
        }
    }

    float top[4][6];                     // row-slot = g0 + w*16 + rq*4 + j
    #pragma unroll
    for (int s4 = 0; s4 < 4; ++s4)
        #pragma unroll
        for (int q = 0; q < 6; ++q) top[s4][q] = FLT_MAX;

    // prologue: stage (nt=0, s=0) into buf0
    {
        const u8* Msrc = Mb + (size_t)(n0c + mband) * C_;
        #pragma unroll
        for (int h = 0; h < 2; ++h)
            #pragma unroll
            for (int i = 0; i < 2; ++i)
                async16(Msrc + (size_t)(i*16 + srow4) * C_ + h*64 + soff,
                        smem + mband*64 + h*8192 + i*1024);
    }
    __syncthreads();                     // drains vmcnt(0): buf0 ready

    const int NT = N_ / NCHUNK / 128;    // 32
    #pragma unroll 1
    for (int nt = 0; nt < NT; ++nt) {
        const int n0 = n0c + nt * 128;

        f32x4 acc[8];
        #pragma unroll
        for (int n = 0; n < 8; ++n) acc[n] = (f32x4)0.f;

        #pragma unroll
        for (int s = 0; s < 4; ++s) {    // K=128 per stage; buf index = s&1 (nt*4 even)
            // ---- prefetch next stage into buf^1 (lands during compute below) ----
            {
                const int nt2 = (s == 3) ? nt + 1 : nt;
                const int s2  = (s + 1) & 3;         // compile-time per unrolled s
                if (nt2 < NT) {
                    const u8* Msrc = Mb + (size_t)(n0c + nt2*128 + mband) * C_ + s2*128;
                    u8* dst = smem + ((s+1)&1)*16384 + mband*64;
                    #pragma unroll
                    for (int h = 0; h < 2; ++h)
                        #pragma unroll
                        for (int i = 0; i < 2; ++i)
                            async16(Msrc + (size_t)(i*16 + srow4) * C_ + h*64 + soff,
                                    dst + h*8192 + i*1024);
                }
            }
            // ---- compute current stage from buf s&1 ----
            const u8* bufp = smem + (s&1)*16384;
            #pragma unroll
            for (int h = 0; h < 2; ++h) {
                const u8* Mh = bufp + h * 8192;
                const u64x2 a = ax[s][h];            // compile-time [s][h]
                #pragma unroll
                for (int n = 0; n < 8; ++n) {
                    u64x2 bv = *(const u64x2*)(Mh + (n*16 + fm) * 64 + pc);
                    // kf0 = low 8B, kf1 = high 8B: K-permutation applied
                    // identically to A and B -> same dot product (verified R7).
                    acc[n] = __builtin_amdgcn_mfma_f32_16x16x32_fp8_fp8(
                        (long)a.x, (long)bv.x, acc[n], 0, 0, 0);
                    acc[n] = __builtin_amdgcn_mfma_f32_16x16x32_fp8_fp8(
                        (long)a.y, (long)bv.y, acc[n], 0, 0, 0);
                }
            }

            if (s == 3) {
                // register epilogue: score = m2[c] - 2*dot (x2 added in finalize)
                float m2w[8];
                #pragma unroll
                for (int n = 0; n < 8; ++n) m2w[n] = m2[n0 + n * 16 + fm];
                #pragma unroll
                for (int j = 0; j < 4; ++j) {
                    float d0 = m2w[0] - 2.f * acc[0][j];
                    float d1 = m2w[1] - 2.f * acc[1][j];
                    float d2 = m2w[2] - 2.f * acc[2][j];
                    float d3 = m2w[3] - 2.f * acc[3][j];
                    float d4 = m2w[4] - 2.f * acc[4][j];
                    float d5 = m2w[5] - 2.f * acc[5][j];
                    float d6 = m2w[6] - 2.f * acc[6][j];
                    float d7 = m2w[7] - 2.f * acc[7][j];
                    float vmin = fminf(fminf(fminf(d0, d1), fminf(d2, d3)),
                                       fminf(fminf(d4, d5), fminf(d6, d7)));
                    float (&tt)[6] = top[j];
                    if (vmin < tt[5]) {      // slow path: rare after first tiles
                        ins6(tt, d0); ins6(tt, d1); ins6(tt, d2); ins6(tt, d3);
                        ins6(tt, d4); ins6(tt, d5); ins6(tt, d6); ins6(tt, d7);
                    }
                }
            }
            __syncthreads();   // drains vmcnt(0): next buf staged; buf s&1 free
        }
    }

    // final merge (single pass): per row, combine 16 fm-lanes' top-6 ->
    // per-chunk top-6 partial. 64 rows x stride 97 -> conflict-free reads.
    // The loop's final barrier guarantees all LDS reads are done before reuse.
    float* Mg = (float*)smem;            // 64*97 = 6208 floats = 24832 B <= 32768
    #pragma unroll
    for (int j = 0; j < 4; ++j) {
        int lrow = w * 16 + rq * 4 + j;
        #pragma unroll
        for (int q = 0; q < 6; ++q)
            Mg[lrow * 97 + fm * 6 + q] = top[j][q];
    }
    __syncthreads();
    if (t < 64) {
        float t6[6];
        #pragma unroll
        for (int q = 0; q < 6; ++q) t6[q] = FLT_MAX;
        const float* row = Mg + t * 97;
        for (int v = 0; v < 96; ++v) ins6(t6, row[v]);
        float* dst = P + ((size_t)(g0 + t) * NCHUNK + blockIdx.y) * 6;
        #pragma unroll
        for (int q = 0; q < 6; ++q) dst[q] = t6[q];
    }
}

// ---------- merge chunks + hinge loss ----------
__global__ void finalize_kernel(const float* __restrict__ P, const float* __restrict__ x2,
                                const float* __restrict__ rp, float* __restrict__ out) {
    int g = blockIdx.x * 256 + threadIdx.x;
    float t6[6];
    #pragma unroll
    for (int q = 0; q < 6; ++q) t6[q] = FLT_MAX;
    const f32x4* pp = (const f32x4*)(P + (size_t)g * (NCHUNK * 6));
    #pragma unroll
    for (int q = 0; q < NCHUNK * 6 / 4; ++q) {
        f32x4 v = pp[q];
        ins6(t6, v.x); ins6(t6, v.y); ins6(t6, v.z); ins6(t6, v.w);
    }
    float x2g = x2[g];
    float rv = rp[0], r2 = rv * rv;
    float s = 0.f;
    #pragma unroll
    for (int i = 0; i < 3; ++i) {
        float d = fmaxf(t6[i] + x2g, 0.f);
        s += fmaxf(d - r2, 0.f);
    }
    #pragma unroll
    for (int i = 3; i < 6; ++i) {
        float d = fmaxf(t6[i] + x2g, 0.f);
        s += fmaxf(r2 - d - ALPHA_, 0.f);
    }
    #pragma unroll
    for (int off = 32; off > 0; off >>= 1) s += __shfl_down(s, off);
    __shared__ float red[4];
    int w = threadIdx.x >> 6, l = threadIdx.x & 63;
    if (l == 0) red[w] = s;
    __syncthreads();
    if (threadIdx.x == 0)
        atomicAdd(out, (red[0] + red[1] + red[2] + red[3]) * SCALE_);
}

// ================= Round-1 fp32 fallback (used only if ws too small) =================
#define TM 64
#define TN 64
#define KC 64
#define LDP 68

__global__ void m2_kernel(const float* __restrict__ mem, float* __restrict__ m2) {
    int wave = threadIdx.x >> 6, lane = threadIdx.x & 63;
    int row = blockIdx.x * 4 + wave;
    const float4* p = reinterpret_cast<const float4*>(mem + (size_t)row * C_);
    float4 a = p[lane], b = p[lane + 64];
    float s = a.x*a.x + a.y*a.y + a.z*a.z + a.w*a.w
            + b.x*b.x + b.y*b.y + b.z*b.z + b.w*b.w;
    #pragma unroll
    for (int off = 32; off > 0; off >>= 1) s += __shfl_down(s, off);
    if (lane == 0) m2[row] = s;
}

__global__ void x2f_kernel(const float* __restrict__ phi, float* __restrict__ x2) {
    int g = blockIdx.x * blockDim.x + threadIdx.x;
    int b = g >> 12;
    int n = g & 4095;
    const float* p = phi + (size_t)b * C_ * HW_ + n;
    float s = 0.f;
    #pragma unroll 8
    for (int c = 0; c < C_; ++c) {
        float v = p[(size_t)c * HW_];
        s = fmaf(v, v, s);
    }
    x2[g] = s;
}

__global__ __launch_bounds__(256) void dist_loss_kernel(
    const float* __restrict__ phi, const float* __restrict__ mem,
    const float* __restrict__ rp,  const float* __restrict__ m2,
    const float* __restrict__ x2,  float* __restrict__ out) {
    __shared__ float smem[2 * TM * LDP];
    float* xs = smem;
    float* ms = smem + TM * LDP;
    const int tid = threadIdx.x;
    const int tx = tid & 15, ty = tid >> 4;
    const int g0 = blockIdx.x * TM;
    const int b = g0 >> 12, n0img = g0 & 4095;
    const float* phiB = phi + (size_t)b * C_ * HW_ + n0img;
    float top[4][6];
    #pragma unroll
    for (int i = 0; i < 4; ++i)
        #pragma unroll
        for (int q = 0; q < 6; ++q) top[i][q] = FLT_MAX;
    float x2v[4];
    #pragma unroll
    for (int i = 0; i < 4; ++i) x2v[i] = x2[g0 + ty * 4 + i];
    for (int nt = 0; nt < N_ / TN; ++nt) {
        const int n0 = nt * TN;
        float acc[4][4];
        #pragma unroll
        for (int i = 0; i < 4; ++i)
            #pragma unroll
            for (int j = 0; j < 4; ++j) acc[i][j] = 0.f;
        for (int s = 0; s < C_ / KC; ++s) {
            const int k0 = s * KC;
            {
                int rr = tid & 63, cb = tid >> 6;
                #pragma unroll
                for (int p = 0; p < 16; ++p) {
                    int cc = p * 4 + cb;
                    xs[rr * LDP + cc] = phiB[(size_t)(k0 + cc) * HW_ + rr];
                }
            }
            {
                int kq = tid & 15, cb = tid >> 4;
                #pragma unroll
                for (int p = 0; p < 4; ++p) {
                    int c = p * 16 + cb;
                    float4 v = *reinterpret_cast<const float4*>(
                        mem + (size_t)(n0 + c) * C_ + k0 + kq * 4);
                    ms[(kq*4+0)*LDP + c] = v.x; ms[(kq*4+1)*LDP + c] = v.y;
                    ms[(kq*4+2)*LDP + c] = v.z; ms[(kq*4+3)*LDP + c] = v.w;
                }
            }
            __syncthreads();
            #pragma unroll
            for (int kq = 0; kq < KC / 4; ++kq) {
                float4 xa[4], mb[4];
                #pragma unroll
                for (int i = 0; i < 4; ++i)
                    xa[i] = *reinterpret_cast<const float4*>(&xs[(ty*4+i)*LDP + kq*4]);
                #pragma unroll
                for (int kk = 0; kk < 4; ++kk)
                    mb[kk] = *reinterpret_cast<const float4*>(&ms[(kq*4+kk)*LDP + tx*4]);
                #pragma unroll
                for (int i = 0; i < 4; ++i) {
                    const float xk[4] = {xa[i].x, xa[i].y, xa[i].z, xa[i].w};
                    #pragma unroll
                    for (int kk = 0; kk < 4; ++kk) {
                        const float mc[4] = {mb[kk].x, mb[kk].y, mb[kk].z, mb[kk].w};
                        #pragma unroll
                        for (int j = 0; j < 4; ++j)
                            acc[i][j] = fmaf(xk[kk], mc[j], acc[i][j]);
                    }
                }
            }
            __syncthreads();
        }
        #pragma unroll
        for (int j = 0; j < 4; ++j) {
            float m2v = m2[n0 + tx * 4 + j];
            #pragma unroll
            for (int i = 0; i < 4; ++i) {
                float d = fmaxf(x2v[i] + m2v - 2.f * acc[i][j], 0.f);
                ins6(top[i], d);
            }
        }
    }
    __syncthreads();
    float* mg = smem;
    #pragma unroll
    for (int i = 0; i < 4; ++i)
        #pragma unroll
        for (int q = 0; q < 6; ++q)
            mg[(ty*4+i)*97 + tx*6 + q] = top[i][q];
    __syncthreads();
    if (tid < 64) {
        float t6[6];
        #pragma unroll
        for (int q = 0; q < 6; ++q) t6[q] = FLT_MAX;
        const float* row = mg + tid * 97;
        for (int v = 0; v < 96; ++v) ins6(t6, row[v]);
        float rv = rp[0], r2 = rv * rv;
        float s = fmaxf(t6[0]-r2,0.f) + fmaxf(t6[1]-r2,0.f) + fmaxf(t6[2]-r2,0.f)
                + fmaxf(r2-t6[3]-ALPHA_,0.f) + fmaxf(r2-t6[4]-ALPHA_,0.f)
                + fmaxf(r2-t6[5]-ALPHA_,0.f);
        #pragma unroll
        for (int off = 32; off > 0; off >>= 1) s += __shfl_down(s, off);
        if (tid == 0) atomicAdd(out, s * SCALE_);
    }
}

extern "C" void kernel_launch(void* const* d_in, const int* in_sizes, int n_in,
                              void* d_out, int out_size, void* d_ws, size_t ws_size,
                              hipStream_t stream) {
    const float* phi = (const float*)d_in[0];
    const float* mem = (const float*)d_in[1];
    const float* rp  = (const float*)d_in[2];
    float* out = (float*)d_out;

    const size_t offX  = 0;
    const size_t offM  = (size_t)R_ * C_;                // Xb fp8: 8 MB
    const size_t offx2 = offM + (size_t)N_ * C_;         // Mb fp8: 8 MB
    const size_t offm2 = offx2 + (size_t)R_ * 4;
    const size_t offP  = offm2 + (size_t)N_ * 4;
    const size_t need  = offP + (size_t)R_ * NCHUNK * 6 * 4;  // ~17.8 MB

    hipMemsetAsync(out, 0, sizeof(float), stream);

    if (ws_size >= need) {
        u8*    Xb = (u8*)((char*)d_ws + offX);
        u8*    Mb = (u8*)((char*)d_ws + offM);
        float* x2 = (float*)((char*)d_ws + offx2);
        float* m2 = (float*)((char*)d_ws + offm2);
        float* P  = (float*)((char*)d_ws + offP);

        hipMemsetAsync(x2, 0, (size_t)R_ * 4, stream);   // x2 accumulated atomically
        conv_mem_kernel<<<N_ / 4, 256, 0, stream>>>(mem, Mb, m2);
        conv_phi_kernel<<<dim3(HW_ / 64, C_ / 64, B_), 256, 0, stream>>>(phi, Xb, x2);
        gemm_topk_kernel<<<dim3(R_ / 64, NCHUNK), 256, 0, stream>>>(Xb, Mb, m2, P);
        finalize_kernel<<<R_ / 256, 256, 0, stream>>>(P, x2, rp, out);
    } else {
        // fp32 fallback (verified round 1)
        float* m2 = (float*)d_ws;
        float* x2 = m2 + N_;
        m2_kernel<<<N_ / 4, 256, 0, stream>>>(mem, m2);
        x2f_kernel<<<R_ / 256, 256, 0, stream>>>(phi, x2);
        dist_loss_kernel<<<R_ / TM, 256, 0, stream>>>(phi, mem, rp, m2, x2, out);
    }
}